// Round 1
// baseline (10563.050 us; speedup 1.0000x reference)
//
#include <hip/hip_runtime.h>
#include <cmath>

#define B_ 64
#define P_ 196
#define ENC_ 2048
#define DEC_ 1024
#define ATT_ 1024
#define EMB_ 1024
#define V_ 10000
#define MAXLEN_ 20
#define TDEC_ 19

// ---------------- static device workspace (avoids ws_size dependence) ----------------
constexpr size_t OFF_ATT1  = 0;                                   // 12544*1024
constexpr size_t OFF_GPART = OFF_ATT1 + (size_t)12544 * 1024;     // 4*64*4096
constexpr size_t OFF_X1    = OFF_GPART + (size_t)4 * 64 * 4096;   // 64*4096
constexpr size_t OFF_X2    = OFF_X1 + (size_t)64 * 4096;          // 64*3072
constexpr size_t OFF_H1    = OFF_X2 + (size_t)64 * 3072;          // 64*1024
constexpr size_t OFF_C1    = OFF_H1 + (size_t)64 * 1024;
constexpr size_t OFF_H2    = OFF_C1 + (size_t)64 * 1024;
constexpr size_t OFF_C2    = OFF_H2 + (size_t)64 * 1024;
constexpr size_t OFF_ATT2  = OFF_C2 + (size_t)64 * 1024;          // 64*1024
constexpr size_t OFF_EM    = OFF_ATT2 + (size_t)64 * 1024;        // 64*2048
constexpr size_t OFF_ALPHA = OFF_EM + (size_t)64 * 2048;          // 64*196
constexpr size_t OFF_AWE   = OFF_ALPHA + (size_t)64 * 196;        // 64*2048
constexpr size_t FBUF_TOTAL = OFF_AWE + (size_t)64 * 2048;

__device__ __align__(16) float g_fbuf[FBUF_TOTAL];
__device__ int g_ibuf[64 + 64 + 64 * MAXLEN_];  // sort_ind, dec_len, caps_sorted

// ---------------- sort + int outputs ----------------
__global__ void k_sort(const int* __restrict__ cl_in, const int* __restrict__ caps_in,
                       int* __restrict__ sind, int* __restrict__ declen, int* __restrict__ caps_s,
                       float* __restrict__ out_caps, float* __restrict__ out_declen,
                       float* __restrict__ out_sind) {
  int i = threadIdx.x;  // 64 threads
  __shared__ int cl[B_];
  cl[i] = cl_in[i];
  __syncthreads();
  int my = cl[i], pos = 0;
  for (int j = 0; j < B_; ++j) {
    int cj = cl[j];
    if (cj > my || (cj == my && j < i)) pos++;
  }
  sind[pos] = i;
  __syncthreads();
  int sb = sind[i];
  int dl = cl[sb] - 1;
  declen[i] = dl;
  out_declen[i] = (float)dl;
  out_sind[i] = (float)sb;
  for (int t = 0; t < MAXLEN_; ++t) {
    int v = caps_in[sb * MAXLEN_ + t];
    caps_s[i * MAXLEN_ + t] = v;
    out_caps[i * MAXLEN_ + t] = (float)v;
  }
}

__global__ void k_init(float* __restrict__ p) {
  p[blockIdx.x * 256 + threadIdx.x] = 0.0f;  // grid covers exactly 4*64*1024
}

// ---------------- encoder mean ----------------
__global__ __launch_bounds__(256) void k_encmean(const float* __restrict__ enc,
                                                 const int* __restrict__ sind,
                                                 float* __restrict__ em) {
  int b = blockIdx.x;
  int sb = sind[b];
  const float* src = enc + (size_t)sb * P_ * ENC_;
  for (int e = threadIdx.x; e < ENC_; e += 256) {
    float s = 0.0f;
    for (int p = 0; p < P_; ++p) s += src[(size_t)p * ENC_ + e];
    em[(size_t)b * ENC_ + e] = s / 196.0f;
  }
}

// ---------------- att1 = enc_sorted @ We^T + be : (12544 x 1024), K=2048 ----------------
__global__ __launch_bounds__(256) void k_att1(const float* __restrict__ enc,
                                              const float* __restrict__ We,
                                              const float* __restrict__ be,
                                              const int* __restrict__ sind,
                                              float* __restrict__ att1) {
  __shared__ __align__(16) float As[16][128];
  __shared__ __align__(16) float Ws[16][64];
  int m0 = blockIdx.x * 128;  // 98 blocks
  int n0 = blockIdx.y * 64;   // 16 blocks
  int tid = threadIdx.x;
  int tn = tid & 15, tm = tid >> 4;
  float acc[8][4] = {};
  for (int k0 = 0; k0 < ENC_; k0 += 16) {
#pragma unroll
    for (int h = 0; h < 2; ++h) {
      int f = tid + h * 256;
      int row = f >> 2, kq = (f & 3) << 2;
      int mg = m0 + row;
      int b = mg / P_;
      int p = mg - b * P_;
      float4 a4 = *(const float4*)(enc + ((size_t)sind[b] * P_ + p) * ENC_ + k0 + kq);
      As[kq + 0][row] = a4.x; As[kq + 1][row] = a4.y;
      As[kq + 2][row] = a4.z; As[kq + 3][row] = a4.w;
    }
    {
      int n = tid >> 2, kq = (tid & 3) << 2;
      float4 w4 = *(const float4*)(We + (size_t)(n0 + n) * ENC_ + k0 + kq);
      Ws[kq + 0][n] = w4.x; Ws[kq + 1][n] = w4.y;
      Ws[kq + 2][n] = w4.z; Ws[kq + 3][n] = w4.w;
    }
    __syncthreads();
#pragma unroll
    for (int k = 0; k < 16; ++k) {
      float4 a0 = *(const float4*)&As[k][tm * 8];
      float4 a1 = *(const float4*)&As[k][tm * 8 + 4];
      float4 w  = *(const float4*)&Ws[k][tn * 4];
      float av[8] = {a0.x, a0.y, a0.z, a0.w, a1.x, a1.y, a1.z, a1.w};
      float wv[4] = {w.x, w.y, w.z, w.w};
#pragma unroll
      for (int i = 0; i < 8; ++i)
#pragma unroll
        for (int j = 0; j < 4; ++j) acc[i][j] += av[i] * wv[j];
    }
    __syncthreads();
  }
#pragma unroll
  for (int i = 0; i < 8; ++i) {
    int m = m0 + tm * 8 + i;
#pragma unroll
    for (int j = 0; j < 4; ++j) {
      int n = n0 + tn * 4 + j;
      att1[(size_t)m * ATT_ + n] = acc[i][j] + be[n];
    }
  }
}

// ---------------- dual (x@W1^T + h@W2^T) with 4-way K-split: out gpart[s][64][4096] ----------------
__global__ __launch_bounds__(256) void k_gemm_dual_split(
    const float* __restrict__ X1, const float* __restrict__ W1, int K1,
    const float* __restrict__ X2, const float* __restrict__ W2, int K2,
    const float* __restrict__ bias1, const float* __restrict__ bias2,
    float* __restrict__ gpart) {
  __shared__ __align__(16) float Xs[32][64];
  __shared__ __align__(16) float Ws[32][64];
  int n0 = blockIdx.x * 64;  // N = 4096, 64 blocks
  int s = blockIdx.y;        // 4 splits
  int kchunk = (K1 + K2) >> 2;  // divisible by 32
  int kbeg = s * kchunk, kend = kbeg + kchunk;
  int tid = threadIdx.x;
  int tn = tid & 15, tm = tid >> 4;
  float acc[4][4] = {};
  for (int k0 = kbeg; k0 < kend; k0 += 32) {
    const float* X; const float* W; int K; int kk;
    if (k0 < K1) { X = X1; W = W1; K = K1; kk = k0; }
    else         { X = X2; W = W2; K = K2; kk = k0 - K1; }
#pragma unroll
    for (int h = 0; h < 2; ++h) {
      int f = tid + h * 256;
      int row = f >> 3, kq = (f & 7) << 2;
      float4 x4 = *(const float4*)(X + (size_t)row * K + kk + kq);
      Xs[kq + 0][row] = x4.x; Xs[kq + 1][row] = x4.y;
      Xs[kq + 2][row] = x4.z; Xs[kq + 3][row] = x4.w;
      float4 w4 = *(const float4*)(W + (size_t)(n0 + row) * K + kk + kq);
      Ws[kq + 0][row] = w4.x; Ws[kq + 1][row] = w4.y;
      Ws[kq + 2][row] = w4.z; Ws[kq + 3][row] = w4.w;
    }
    __syncthreads();
#pragma unroll
    for (int k = 0; k < 32; ++k) {
      float4 x4 = *(const float4*)&Xs[k][tm * 4];
      float4 w4 = *(const float4*)&Ws[k][tn * 4];
      float xv[4] = {x4.x, x4.y, x4.z, x4.w};
      float wv[4] = {w4.x, w4.y, w4.z, w4.w};
#pragma unroll
      for (int i = 0; i < 4; ++i)
#pragma unroll
        for (int j = 0; j < 4; ++j) acc[i][j] += xv[i] * wv[j];
    }
    __syncthreads();
  }
  float* outp = gpart + (size_t)s * 64 * 4096;
#pragma unroll
  for (int i = 0; i < 4; ++i) {
    int m = tm * 4 + i;
#pragma unroll
    for (int j = 0; j < 4; ++j) {
      int n = n0 + tn * 4 + j;
      float v = acc[i][j];
      if (s == 0) v += bias1[n] + bias2[n];
      outp[(size_t)m * 4096 + n] = v;
    }
  }
}

// ---------------- LSTM gates: sum 4 K-split partials, update h/c with active mask ----------------
__global__ __launch_bounds__(256) void k_gates(const float* __restrict__ gpart,
                                               float* __restrict__ h, float* __restrict__ c,
                                               const int* __restrict__ declen, int t) {
  int idx = blockIdx.x * 256 + threadIdx.x;  // 64*1024
  int b = idx >> 10, j = idx & 1023;
  const float* gb = gpart + (size_t)b * 4096;
  float gi = 0.f, gf = 0.f, gg = 0.f, go = 0.f;
#pragma unroll
  for (int s = 0; s < 4; ++s) {
    const float* p = gb + (size_t)s * 64 * 4096;
    gi += p[j]; gf += p[j + 1024]; gg += p[j + 2048]; go += p[j + 3072];
  }
  float si = 1.0f / (1.0f + expf(-gi));
  float sf = 1.0f / (1.0f + expf(-gf));
  float so = 1.0f / (1.0f + expf(-go));
  float cn = sf * c[idx] + si * tanhf(gg);
  float hn = so * tanhf(cn);
  if (t < declen[b]) { h[idx] = hn; c[idx] = cn; }
}

// ---------------- generic skinny GEMM: C[64][N] = X@W^T + bias, optional mask->0 ----------------
__global__ __launch_bounds__(256) void k_gemm_out(
    const float* __restrict__ X, const float* __restrict__ W, int K,
    const float* __restrict__ bias, float* __restrict__ C, int N, long long ldc,
    const int* __restrict__ declen, int t) {
  __shared__ __align__(16) float Xs[32][64];
  __shared__ __align__(16) float Ws[32][64];
  int n0 = blockIdx.x * 64;
  int tid = threadIdx.x;
  int tn = tid & 15, tm = tid >> 4;
  float acc[4][4] = {};
  for (int k0 = 0; k0 < K; k0 += 32) {
#pragma unroll
    for (int h = 0; h < 2; ++h) {
      int f = tid + h * 256;
      int row = f >> 3, kq = (f & 7) << 2;
      float4 x4 = *(const float4*)(X + (size_t)row * K + k0 + kq);
      Xs[kq + 0][row] = x4.x; Xs[kq + 1][row] = x4.y;
      Xs[kq + 2][row] = x4.z; Xs[kq + 3][row] = x4.w;
      int n = n0 + row;
      float4 w4 = make_float4(0.f, 0.f, 0.f, 0.f);
      if (n < N) w4 = *(const float4*)(W + (size_t)n * K + k0 + kq);
      Ws[kq + 0][row] = w4.x; Ws[kq + 1][row] = w4.y;
      Ws[kq + 2][row] = w4.z; Ws[kq + 3][row] = w4.w;
    }
    __syncthreads();
#pragma unroll
    for (int k = 0; k < 32; ++k) {
      float4 x4 = *(const float4*)&Xs[k][tm * 4];
      float4 w4 = *(const float4*)&Ws[k][tn * 4];
      float xv[4] = {x4.x, x4.y, x4.z, x4.w};
      float wv[4] = {w4.x, w4.y, w4.z, w4.w};
#pragma unroll
      for (int i = 0; i < 4; ++i)
#pragma unroll
        for (int j = 0; j < 4; ++j) acc[i][j] += xv[i] * wv[j];
    }
    __syncthreads();
  }
#pragma unroll
  for (int i = 0; i < 4; ++i) {
    int m = tm * 4 + i;
    bool act = (declen == nullptr) || (t < declen[m]);
#pragma unroll
    for (int j = 0; j < 4; ++j) {
      int n = n0 + tn * 4 + j;
      if (n < N) {
        float v = acc[i][j] + bias[n];
        C[(long long)m * ldc + n] = act ? v : 0.0f;
      }
    }
  }
}

// ---------------- x1 = [h2, enc_mean, embed] ----------------
__global__ void k_x1(const float* __restrict__ h2, const float* __restrict__ em,
                     const float* __restrict__ emb_table, const int* __restrict__ caps_s,
                     int t, float* __restrict__ x1) {
  int idx = blockIdx.x * 256 + threadIdx.x;  // 64*4096
  int b = idx >> 12, col = idx & 4095;
  float v;
  if (col < DEC_) v = h2[b * DEC_ + col];
  else if (col < DEC_ + ENC_) v = em[b * ENC_ + (col - DEC_)];
  else v = emb_table[(size_t)caps_s[b * MAXLEN_ + t] * EMB_ + (col - DEC_ - ENC_)];
  x1[idx] = v;
}

// ---------------- x2 = [awe, h1] ----------------
__global__ void k_x2(const float* __restrict__ awe, const float* __restrict__ h1,
                     float* __restrict__ x2) {
  int idx = blockIdx.x * 256 + threadIdx.x;  // 64*3072
  int b = idx / 3072;
  int col = idx - b * 3072;
  x2[idx] = (col < ENC_) ? awe[b * ENC_ + col] : h1[b * DEC_ + (col - ENC_)];
}

// ---------------- e[b,p] = Wf . relu(att1[b,p,:] + att2[b,:]) + bf ----------------
__global__ __launch_bounds__(256) void k_e(const float* __restrict__ att1,
                                           const float* __restrict__ att2,
                                           const float* __restrict__ Wf,
                                           const float* __restrict__ bf,
                                           float* __restrict__ e) {
  int wave = threadIdx.x >> 6, lane = threadIdx.x & 63;
  int b = blockIdx.x / 49;
  int p = (blockIdx.x % 49) * 4 + wave;  // 196 = 49*4
  const float* a1 = att1 + ((size_t)b * P_ + p) * ATT_;
  const float* a2 = att2 + (size_t)b * ATT_;
  float s = 0.0f;
  for (int a = lane; a < ATT_; a += 64) {
    float v = a1[a] + a2[a];
    s += Wf[a] * fmaxf(v, 0.0f);
  }
#pragma unroll
  for (int off = 32; off > 0; off >>= 1) s += __shfl_down(s, off);
  if (lane == 0) e[b * P_ + p] = s + bf[0];
}

// ---------------- softmax over p (in place) ----------------
__global__ void k_softmax(float* __restrict__ e) {
  int b = blockIdx.x, lane = threadIdx.x;  // 64 threads
  float vals[4];
  float mx = -1e30f;
#pragma unroll
  for (int q = 0; q < 4; ++q) {
    int p = lane + q * 64;
    vals[q] = (p < P_) ? e[b * P_ + p] : -1e30f;
    mx = fmaxf(mx, vals[q]);
  }
#pragma unroll
  for (int off = 32; off > 0; off >>= 1) mx = fmaxf(mx, __shfl_xor(mx, off));
  float sum = 0.0f;
#pragma unroll
  for (int q = 0; q < 4; ++q) {
    int p = lane + q * 64;
    vals[q] = (p < P_) ? expf(vals[q] - mx) : 0.0f;
    sum += vals[q];
  }
#pragma unroll
  for (int off = 32; off > 0; off >>= 1) sum += __shfl_xor(sum, off);
  float inv = 1.0f / sum;
#pragma unroll
  for (int q = 0; q < 4; ++q) {
    int p = lane + q * 64;
    if (p < P_) e[b * P_ + p] = vals[q] * inv;
  }
}

// ---------------- awe[b,e] = sum_p enc[sb,p,e] * alpha[b,p] ----------------
__global__ __launch_bounds__(256) void k_awe(const float* __restrict__ enc,
                                             const int* __restrict__ sind,
                                             const float* __restrict__ alpha,
                                             float* __restrict__ awe) {
  int b = blockIdx.x;
  __shared__ float al[P_];
  for (int p = threadIdx.x; p < P_; p += 256) al[p] = alpha[b * P_ + p];
  __syncthreads();
  const float* src = enc + (size_t)sind[b] * P_ * ENC_;
  for (int e = threadIdx.x; e < ENC_; e += 256) {
    float s = 0.0f;
    for (int p = 0; p < P_; ++p) s += src[(size_t)p * ENC_ + e] * al[p];
    awe[(size_t)b * ENC_ + e] = s;
  }
}

// ---------------- host ----------------
extern "C" void kernel_launch(void* const* d_in, const int* in_sizes, int n_in,
                              void* d_out, int out_size, void* d_ws, size_t ws_size,
                              hipStream_t stream) {
  (void)in_sizes; (void)n_in; (void)d_ws; (void)ws_size; (void)out_size;
  const float* enc  = (const float*)d_in[0];
  const int*   caps = (const int*)d_in[1];
  const int*   cl   = (const int*)d_in[2];
  const float* emb  = (const float*)d_in[3];
  const float* We   = (const float*)d_in[4];
  const float* be   = (const float*)d_in[5];
  const float* Wd   = (const float*)d_in[6];
  const float* bd   = (const float*)d_in[7];
  const float* Wf   = (const float*)d_in[8];
  const float* bf   = (const float*)d_in[9];
  const float* Wih1 = (const float*)d_in[10];
  const float* Whh1 = (const float*)d_in[11];
  const float* bih1 = (const float*)d_in[12];
  const float* bhh1 = (const float*)d_in[13];
  const float* Wih2 = (const float*)d_in[14];
  const float* Whh2 = (const float*)d_in[15];
  const float* bih2 = (const float*)d_in[16];
  const float* bhh2 = (const float*)d_in[17];
  const float* Wfc1 = (const float*)d_in[18];
  const float* bfc1 = (const float*)d_in[19];
  const float* Wfc  = (const float*)d_in[20];
  const float* bfc  = (const float*)d_in[21];
  float* out = (float*)d_out;

  float* fb = nullptr;
  int* ib = nullptr;
  hipGetSymbolAddress((void**)&fb, HIP_SYMBOL(g_fbuf));
  hipGetSymbolAddress((void**)&ib, HIP_SYMBOL(g_ibuf));

  float* att1  = fb + OFF_ATT1;
  float* gpart = fb + OFF_GPART;
  float* x1    = fb + OFF_X1;
  float* x2    = fb + OFF_X2;
  float* h1    = fb + OFF_H1;
  float* c1    = fb + OFF_C1;
  float* h2    = fb + OFF_H2;
  float* c2    = fb + OFF_C2;
  float* att2  = fb + OFF_ATT2;
  float* em    = fb + OFF_EM;
  float* alpha = fb + OFF_ALPHA;
  float* awe   = fb + OFF_AWE;
  int* sind   = ib;
  int* declen = ib + 64;
  int* caps_s = ib + 128;

  float* out_preds  = out;
  float* out_preds1 = out + (size_t)B_ * TDEC_ * V_;
  float* out_caps   = out + 2ull * B_ * TDEC_ * V_;
  float* out_declen = out_caps + B_ * MAXLEN_;
  float* out_sind   = out_declen + B_;

  k_sort<<<1, 64, 0, stream>>>(cl, caps, sind, declen, caps_s, out_caps, out_declen, out_sind);
  k_init<<<1024, 256, 0, stream>>>(h1);  // zeroes h1,c1,h2,c2 (contiguous)
  k_encmean<<<64, 256, 0, stream>>>(enc, sind, em);
  k_att1<<<dim3(98, 16), 256, 0, stream>>>(enc, We, be, sind, att1);

  for (int t = 0; t < TDEC_; ++t) {
    k_x1<<<1024, 256, 0, stream>>>(h2, em, emb, caps_s, t, x1);
    k_gemm_dual_split<<<dim3(64, 4), 256, 0, stream>>>(x1, Wih1, 4096, h1, Whh1, 1024,
                                                       bih1, bhh1, gpart);
    k_gates<<<256, 256, 0, stream>>>(gpart, h1, c1, declen, t);
    k_gemm_out<<<16, 256, 0, stream>>>(h1, Wd, 1024, bd, att2, ATT_, (long long)ATT_,
                                       nullptr, 0);
    k_e<<<3136, 256, 0, stream>>>(att1, att2, Wf, bf, alpha);
    k_softmax<<<64, 64, 0, stream>>>(alpha);
    k_awe<<<64, 256, 0, stream>>>(enc, sind, alpha, awe);
    k_gemm_out<<<157, 256, 0, stream>>>(h1, Wfc1, 1024, bfc1, out_preds1 + (size_t)t * V_,
                                        V_, (long long)TDEC_ * V_, declen, t);
    k_x2<<<768, 256, 0, stream>>>(awe, h1, x2);
    k_gemm_dual_split<<<dim3(64, 4), 256, 0, stream>>>(x2, Wih2, 3072, h2, Whh2, 1024,
                                                       bih2, bhh2, gpart);
    k_gates<<<256, 256, 0, stream>>>(gpart, h2, c2, declen, t);
    k_gemm_out<<<157, 256, 0, stream>>>(h2, Wfc, 1024, bfc, out_preds + (size_t)t * V_,
                                        V_, (long long)TDEC_ * V_, declen, t);
  }
}

// Round 3
// 3390.016 us; speedup vs baseline: 3.1159x; 3.1159x over previous
//
#include <hip/hip_runtime.h>
#include <cmath>

#define B_ 64
#define P_ 196
#define ENC_ 2048
#define DEC_ 1024
#define V_ 10000
#define MAXLEN_ 20
#define TDEC_ 19

typedef __attribute__((ext_vector_type(8))) short bf16x8;
typedef __attribute__((ext_vector_type(4))) float f32x4;

// ---------------- static device buffers ----------------
__device__ __align__(16) short g_encb[(size_t)12544 * 2048];       // sorted enc, bf16
__device__ __align__(16) short g_att1[(size_t)12544 * 1024];       // att1, bf16
__device__ __align__(16) short g_Wcat1[(size_t)4096 * 5120];       // [Wih1(4096) | Whh1(1024)]
__device__ __align__(16) short g_Wcat2[(size_t)4096 * 4096];       // [Wih2(3072) | Whh2(1024)]
__device__ __align__(16) short g_Web[(size_t)1024 * 2048];
__device__ __align__(16) short g_Wdb[(size_t)1024 * 1024];
__device__ __align__(16) short g_Wfc1b[(size_t)10000 * 1024];
__device__ __align__(16) short g_Wfcb[(size_t)10000 * 1024];
__device__ __align__(16) short g_xc1[64 * 5120];  // [h2 | em | emb_t | h1]
__device__ __align__(16) short g_xc2[64 * 4096];  // [awe | h1 | h2]
__device__ __align__(16) float g_part[2 * 64 * 10000];   // >= 4*64*4096
__device__ __align__(16) float g_att2p[2 * 64 * 1024];
__device__ __align__(16) float g_alpha[64 * P_];
__device__ __align__(16) float g_c1[64 * 1024];
__device__ __align__(16) float g_c2[64 * 1024];
__device__ int g_ibuf[64 + 64 + 64 * MAXLEN_];

__device__ __forceinline__ short f2b(float f) {
  unsigned u = __float_as_uint(f);
  u += 0x7FFFu + ((u >> 16) & 1u);
  return (short)(u >> 16);
}
__device__ __forceinline__ float b2f(short s) {
  return __uint_as_float(((unsigned)(unsigned short)s) << 16);
}

// ---------------- sort + int-ish outputs ----------------
__global__ void k_sort(const int* __restrict__ cl_in, const int* __restrict__ caps_in,
                       int* __restrict__ sind, int* __restrict__ declen, int* __restrict__ caps_s,
                       float* __restrict__ out_caps, float* __restrict__ out_declen,
                       float* __restrict__ out_sind) {
  int i = threadIdx.x;  // 64 threads
  __shared__ int cl[B_];
  cl[i] = cl_in[i];
  __syncthreads();
  int my = cl[i], pos = 0;
  for (int j = 0; j < B_; ++j) {
    int cj = cl[j];
    if (cj > my || (cj == my && j < i)) pos++;
  }
  sind[pos] = i;
  __syncthreads();
  int sb = sind[i];
  int dl = cl[sb] - 1;
  declen[i] = dl;
  out_declen[i] = (float)dl;
  out_sind[i] = (float)sb;
  for (int t = 0; t < MAXLEN_; ++t) {
    int v = caps_in[sb * MAXLEN_ + t];
    caps_s[i * MAXLEN_ + t] = v;
    out_caps[i * MAXLEN_ + t] = (float)v;
  }
}

// zero c1,c2 (fp32)
__global__ void k_zeroc(float* __restrict__ c1, float* __restrict__ c2) {
  int idx = blockIdx.x * 256 + threadIdx.x;  // 131072
  if (idx < 65536) c1[idx] = 0.0f; else c2[idx - 65536] = 0.0f;
}
// zero bf16 h-slots in xc1/xc2
__global__ void k_zerohs(short* __restrict__ xc1, short* __restrict__ xc2) {
  int idx = blockIdx.x * 256 + threadIdx.x;  // 64*4096
  int b = idx >> 12, col = idx & 4095;
  if (col < 1024) xc1[b * 5120 + col] = 0;                       // h2 slot
  else if (col < 2048) xc1[b * 5120 + 4096 + (col - 1024)] = 0;  // h1 slot
  else xc2[b * 4096 + col] = 0;                                  // h1,h2 slots [2048,4096)
}

// gather-sort + fp32->bf16 convert encoder
__global__ __launch_bounds__(256) void k_encprep(const float* __restrict__ enc,
                                                 const int* __restrict__ sind,
                                                 short* __restrict__ encb) {
  int mg = blockIdx.x;  // 12544
  int b = mg / P_, p = mg - b * P_;
  const float* src = enc + ((size_t)sind[b] * P_ + p) * ENC_ + threadIdx.x * 8;
  short* dst = encb + (size_t)mg * ENC_ + threadIdx.x * 8;
  float4 a = *(const float4*)src;
  float4 c = *(const float4*)(src + 4);
  bf16x8 v;
  v[0] = f2b(a.x); v[1] = f2b(a.y); v[2] = f2b(a.z); v[3] = f2b(a.w);
  v[4] = f2b(c.x); v[5] = f2b(c.y); v[6] = f2b(c.z); v[7] = f2b(c.w);
  *(bf16x8*)dst = v;
}

// enc mean (over bf16 enc) -> bf16 into xc1 em slot
__global__ __launch_bounds__(256) void k_encmeanb(const short* __restrict__ encb,
                                                  short* __restrict__ xc1) {
  int b = blockIdx.x;
  int col0 = threadIdx.x * 8;
  const short* src = encb + (size_t)b * P_ * ENC_ + col0;
  float acc[8] = {};
  for (int p = 0; p < P_; ++p) {
    bf16x8 v = *(const bf16x8*)(src + (size_t)p * ENC_);
#pragma unroll
    for (int j = 0; j < 8; ++j) acc[j] += b2f(v[j]);
  }
#pragma unroll
  for (int j = 0; j < 8; ++j) xc1[b * 5120 + 1024 + col0 + j] = f2b(acc[j] * (1.0f / 196.0f));
}

// strided fp32 -> bf16 weight convert: dst[r*ld+off+k] = src[r*K+k]
__global__ void k_f2bs(const float* __restrict__ src, int K, short* __restrict__ dst,
                       int ld, int off) {
  long long idx = (long long)(blockIdx.x * 256 + threadIdx.x) * 8;
  int r = (int)(idx / K), k = (int)(idx % K);
  const float* s = src + (size_t)r * K + k;
  float4 a = *(const float4*)s;
  float4 c = *(const float4*)(s + 4);
  bf16x8 v;
  v[0] = f2b(a.x); v[1] = f2b(a.y); v[2] = f2b(a.z); v[3] = f2b(a.w);
  v[4] = f2b(c.x); v[5] = f2b(c.y); v[6] = f2b(c.z); v[7] = f2b(c.w);
  *(bf16x8*)(dst + (size_t)r * ld + off + k) = v;
}

// ---------------- att1 = encb @ We^T + be -> bf16 (12544x1024, K=2048) ----------------
__global__ __launch_bounds__(512) void k_att1_mfma(const short* __restrict__ A,
                                                   const short* __restrict__ W,
                                                   const float* __restrict__ be,
                                                   short* __restrict__ Cb) {
  int wave = threadIdx.x >> 6, lane = threadIdx.x & 63;
  int m0 = blockIdx.x * 128 + (wave >> 2) * 64;
  int n0 = blockIdx.y * 256 + (wave & 3) * 64;
  int lr = lane & 15, lk = (lane >> 4) * 8;
  f32x4 acc[4][4] = {};
  const short* Ab = A + (size_t)(m0 + lr) * ENC_ + lk;
  const short* Wb = W + (size_t)(n0 + lr) * ENC_ + lk;
  for (int k0 = 0; k0 < ENC_; k0 += 32) {
    bf16x8 a[4], b[4];
#pragma unroll
    for (int i = 0; i < 4; ++i) a[i] = *(const bf16x8*)(Ab + (size_t)i * 16 * ENC_ + k0);
#pragma unroll
    for (int j = 0; j < 4; ++j) b[j] = *(const bf16x8*)(Wb + (size_t)j * 16 * ENC_ + k0);
#pragma unroll
    for (int i = 0; i < 4; ++i)
#pragma unroll
      for (int j = 0; j < 4; ++j)
        acc[i][j] = __builtin_amdgcn_mfma_f32_16x16x32_bf16(a[i], b[j], acc[i][j], 0, 0, 0);
  }
  int rr = (lane >> 4) * 4, cc = lane & 15;
#pragma unroll
  for (int i = 0; i < 4; ++i)
#pragma unroll
    for (int j = 0; j < 4; ++j) {
      int n = n0 + j * 16 + cc;
      float bn = be[n];
#pragma unroll
      for (int r = 0; r < 4; ++r) {
        int m = m0 + i * 16 + rr + r;
        Cb[(size_t)m * 1024 + n] = f2b(acc[i][j][r] + bn);
      }
    }
}

// ---------------- generic skinny MFMA GEMM: part[s][64][N] = A[64xK] @ W[NxK]^T chunk ----------------
__global__ __launch_bounds__(256) void k_skinny(const short* __restrict__ A, int lda,
                                                const short* __restrict__ W, int ldw,
                                                int N, int kchunk, float* __restrict__ part) {
  int wave = threadIdx.x >> 6, lane = threadIdx.x & 63;
  int n0 = blockIdx.x * 128 + wave * 32;
  int kb = blockIdx.y * kchunk;
  int lr = lane & 15, lk = (lane >> 4) * 8;
  f32x4 acc[4][2] = {};
  const short* Ab = A + (size_t)lr * lda + kb + lk;
  int nr0 = n0 + lr, nr1 = n0 + 16 + lr;
  bool ok0 = nr0 < N, ok1 = nr1 < N;
  const short* Wb0 = W + (size_t)(ok0 ? nr0 : 0) * ldw + kb + lk;
  const short* Wb1 = W + (size_t)(ok1 ? nr1 : 0) * ldw + kb + lk;
  const bf16x8 zv = {0, 0, 0, 0, 0, 0, 0, 0};
  for (int k0 = 0; k0 < kchunk; k0 += 32) {
    bf16x8 a[4], b0, b1;
#pragma unroll
    for (int i = 0; i < 4; ++i) a[i] = *(const bf16x8*)(Ab + (size_t)i * 16 * lda + k0);
    b0 = ok0 ? *(const bf16x8*)(Wb0 + k0) : zv;
    b1 = ok1 ? *(const bf16x8*)(Wb1 + k0) : zv;
#pragma unroll
    for (int i = 0; i < 4; ++i) {
      acc[i][0] = __builtin_amdgcn_mfma_f32_16x16x32_bf16(a[i], b0, acc[i][0], 0, 0, 0);
      acc[i][1] = __builtin_amdgcn_mfma_f32_16x16x32_bf16(a[i], b1, acc[i][1], 0, 0, 0);
    }
  }
  float* po = part + (size_t)blockIdx.y * 64 * N;
  int rr = (lane >> 4) * 4, cc = lane & 15;
#pragma unroll
  for (int i = 0; i < 4; ++i)
#pragma unroll
    for (int j = 0; j < 2; ++j) {
      int n = n0 + j * 16 + cc;
      if (n < N) {
#pragma unroll
        for (int r = 0; r < 4; ++r) {
          int m = i * 16 + rr + r;
          po[(size_t)m * N + n] = acc[i][j][r];
        }
      }
    }
}

// ---------------- LSTM gates: sum 4 partials + biases, update c, write h as bf16 ----------------
__global__ void k_gates(const float* __restrict__ part, const float* __restrict__ bih,
                        const float* __restrict__ bhh, float* __restrict__ c,
                        short* __restrict__ dst1, int ld1, short* __restrict__ dst2, int ld2,
                        const int* __restrict__ declen, int t) {
  int idx = blockIdx.x * 256 + threadIdx.x;  // 65536
  int b = idx >> 10, j = idx & 1023;
  const float* pb = part + (size_t)b * 4096;
  float gi = bih[j] + bhh[j];
  float gf = bih[1024 + j] + bhh[1024 + j];
  float gg = bih[2048 + j] + bhh[2048 + j];
  float go = bih[3072 + j] + bhh[3072 + j];
#pragma unroll
  for (int s = 0; s < 4; ++s) {
    const float* p = pb + (size_t)s * 64 * 4096;
    gi += p[j]; gf += p[j + 1024]; gg += p[j + 2048]; go += p[j + 3072];
  }
  float si = 1.0f / (1.0f + expf(-gi));
  float sf = 1.0f / (1.0f + expf(-gf));
  float so = 1.0f / (1.0f + expf(-go));
  float cn = sf * c[idx] + si * tanhf(gg);
  float hn = so * tanhf(cn);
  if (t < declen[b]) {
    c[idx] = cn;
    short hb = f2b(hn);
    dst1[b * ld1 + j] = hb;
    dst2[b * ld2 + j] = hb;
  }
}

// ---------------- embed gather -> bf16 into xc1 emb slot ----------------
__global__ void k_embt(const float* __restrict__ emb, const int* __restrict__ caps_s,
                       int t, short* __restrict__ xc1) {
  int idx = blockIdx.x * 256 + threadIdx.x;  // 65536
  int b = idx >> 10, col = idx & 1023;
  xc1[b * 5120 + 3072 + col] = f2b(emb[(size_t)caps_s[b * MAXLEN_ + t] * 1024 + col]);
}

// ---------------- e[b,p] = Wf . relu(att1_b[b,p,:] + att2) + bf ----------------
__global__ __launch_bounds__(256) void k_e(const short* __restrict__ att1,
                                           const float* __restrict__ att2p,
                                           const float* __restrict__ bd,
                                           const float* __restrict__ Wf,
                                           const float* __restrict__ bf,
                                           float* __restrict__ e) {
  __shared__ float a2[1024];
  int b = blockIdx.x / 49, pq = blockIdx.x % 49;
  for (int i = threadIdx.x; i < 1024; i += 256)
    a2[i] = att2p[b * 1024 + i] + att2p[65536 + b * 1024 + i] + bd[i];
  __syncthreads();
  int wave = threadIdx.x >> 6, lane = threadIdx.x & 63;
  int p = pq * 4 + wave;
  const short* a1 = att1 + ((size_t)(b * P_ + p)) * 1024;
  float s = 0.0f;
#pragma unroll
  for (int a0 = lane * 8; a0 < 1024; a0 += 512) {
    bf16x8 v = *(const bf16x8*)(a1 + a0);
#pragma unroll
    for (int j = 0; j < 8; ++j) {
      float vv = b2f(v[j]) + a2[a0 + j];
      s += Wf[a0 + j] * fmaxf(vv, 0.0f);
    }
  }
#pragma unroll
  for (int off = 32; off > 0; off >>= 1) s += __shfl_down(s, off);
  if (lane == 0) e[b * P_ + p] = s + bf[0];
}

// ---------------- softmax over p (in place) ----------------
__global__ void k_softmax(float* __restrict__ e) {
  int b = blockIdx.x, lane = threadIdx.x;  // 64 threads
  float vals[4];
  float mx = -1e30f;
#pragma unroll
  for (int q = 0; q < 4; ++q) {
    int p = lane + q * 64;
    vals[q] = (p < P_) ? e[b * P_ + p] : -1e30f;
    mx = fmaxf(mx, vals[q]);
  }
#pragma unroll
  for (int off = 32; off > 0; off >>= 1) mx = fmaxf(mx, __shfl_xor(mx, off));
  float sum = 0.0f;
#pragma unroll
  for (int q = 0; q < 4; ++q) {
    int p = lane + q * 64;
    vals[q] = (p < P_) ? expf(vals[q] - mx) : 0.0f;
    sum += vals[q];
  }
#pragma unroll
  for (int off = 32; off > 0; off >>= 1) sum += __shfl_xor(sum, off);
  float inv = 1.0f / sum;
#pragma unroll
  for (int q = 0; q < 4; ++q) {
    int p = lane + q * 64;
    if (p < P_) e[b * P_ + p] = vals[q] * inv;
  }
}

// ---------------- awe -> bf16 into xc2 awe slot ----------------
__global__ __launch_bounds__(256) void k_awe(const short* __restrict__ encb,
                                             const float* __restrict__ alpha,
                                             short* __restrict__ xc2) {
  int b = blockIdx.x;
  __shared__ float al[P_];
  for (int i = threadIdx.x; i < P_; i += 256) al[i] = alpha[b * P_ + i];
  __syncthreads();
  int col0 = threadIdx.x * 8;
  const short* src = encb + (size_t)b * P_ * ENC_ + col0;
  float acc[8] = {};
#pragma unroll 4
  for (int p = 0; p < P_; ++p) {
    bf16x8 v = *(const bf16x8*)(src + (size_t)p * ENC_);
    float ap = al[p];
#pragma unroll
    for (int j = 0; j < 8; ++j) acc[j] += ap * b2f(v[j]);
  }
#pragma unroll
  for (int j = 0; j < 8; ++j) xc2[b * 4096 + col0 + j] = f2b(acc[j]);
}

// ---------------- head fixup: sum 2 partials + bias, mask, write ----------------
__global__ void k_headfix(const float* __restrict__ part, const float* __restrict__ bias,
                          float* __restrict__ outp, const int* __restrict__ declen, int t) {
  int idx = blockIdx.x * 256 + threadIdx.x;  // 640000
  int b = idx / V_, v = idx - b * V_;
  float val = part[(size_t)b * V_ + v] + part[(size_t)64 * V_ + b * V_ + v] + bias[v];
  outp[(size_t)b * TDEC_ * V_ + v] = (t < declen[b]) ? val : 0.0f;
}

// ---------------- host ----------------
extern "C" void kernel_launch(void* const* d_in, const int* in_sizes, int n_in,
                              void* d_out, int out_size, void* d_ws, size_t ws_size,
                              hipStream_t stream) {
  (void)in_sizes; (void)n_in; (void)d_ws; (void)ws_size; (void)out_size;
  const float* enc  = (const float*)d_in[0];
  const int*   caps = (const int*)d_in[1];
  const int*   cl   = (const int*)d_in[2];
  const float* emb  = (const float*)d_in[3];
  const float* We   = (const float*)d_in[4];
  const float* be   = (const float*)d_in[5];
  const float* Wd   = (const float*)d_in[6];
  const float* bd   = (const float*)d_in[7];
  const float* Wf   = (const float*)d_in[8];
  const float* bf   = (const float*)d_in[9];
  const float* Wih1 = (const float*)d_in[10];
  const float* Whh1 = (const float*)d_in[11];
  const float* bih1 = (const float*)d_in[12];
  const float* bhh1 = (const float*)d_in[13];
  const float* Wih2 = (const float*)d_in[14];
  const float* Whh2 = (const float*)d_in[15];
  const float* bih2 = (const float*)d_in[16];
  const float* bhh2 = (const float*)d_in[17];
  const float* Wfc1 = (const float*)d_in[18];
  const float* bfc1 = (const float*)d_in[19];
  const float* Wfc  = (const float*)d_in[20];
  const float* bfc  = (const float*)d_in[21];
  float* out = (float*)d_out;

  short *encb, *att1, *Wc1, *Wc2, *Web, *Wdb, *Wfc1b, *Wfcb, *xc1, *xc2;
  float *part, *att2p, *alpha, *c1, *c2;
  int* ib;
  hipGetSymbolAddress((void**)&encb, HIP_SYMBOL(g_encb));
  hipGetSymbolAddress((void**)&att1, HIP_SYMBOL(g_att1));
  hipGetSymbolAddress((void**)&Wc1, HIP_SYMBOL(g_Wcat1));
  hipGetSymbolAddress((void**)&Wc2, HIP_SYMBOL(g_Wcat2));
  hipGetSymbolAddress((void**)&Web, HIP_SYMBOL(g_Web));
  hipGetSymbolAddress((void**)&Wdb, HIP_SYMBOL(g_Wdb));
  hipGetSymbolAddress((void**)&Wfc1b, HIP_SYMBOL(g_Wfc1b));
  hipGetSymbolAddress((void**)&Wfcb, HIP_SYMBOL(g_Wfcb));
  hipGetSymbolAddress((void**)&xc1, HIP_SYMBOL(g_xc1));
  hipGetSymbolAddress((void**)&xc2, HIP_SYMBOL(g_xc2));
  hipGetSymbolAddress((void**)&part, HIP_SYMBOL(g_part));
  hipGetSymbolAddress((void**)&att2p, HIP_SYMBOL(g_att2p));
  hipGetSymbolAddress((void**)&alpha, HIP_SYMBOL(g_alpha));
  hipGetSymbolAddress((void**)&c1, HIP_SYMBOL(g_c1));
  hipGetSymbolAddress((void**)&c2, HIP_SYMBOL(g_c2));
  hipGetSymbolAddress((void**)&ib, HIP_SYMBOL(g_ibuf));
  int* sind = ib;
  int* declen = ib + 64;
  int* caps_s = ib + 128;

  float* out_preds  = out;
  float* out_preds1 = out + (size_t)B_ * TDEC_ * V_;
  float* out_caps   = out + 2ull * B_ * TDEC_ * V_;
  float* out_declen = out_caps + B_ * MAXLEN_;
  float* out_sind   = out_declen + B_;

  // ---- preprocessing ----
  k_sort<<<1, 64, 0, stream>>>(cl, caps, sind, declen, caps_s, out_caps, out_declen, out_sind);
  k_zeroc<<<512, 256, 0, stream>>>(c1, c2);
  k_zerohs<<<1024, 256, 0, stream>>>(xc1, xc2);
  k_encprep<<<12544, 256, 0, stream>>>(enc, sind, encb);
  k_encmeanb<<<64, 256, 0, stream>>>(encb, xc1);
  // weight converts (grids = elems/2048)
  k_f2bs<<<8192, 256, 0, stream>>>(Wih1, 4096, Wc1, 5120, 0);
  k_f2bs<<<2048, 256, 0, stream>>>(Whh1, 1024, Wc1, 5120, 4096);
  k_f2bs<<<6144, 256, 0, stream>>>(Wih2, 3072, Wc2, 4096, 0);
  k_f2bs<<<2048, 256, 0, stream>>>(Whh2, 1024, Wc2, 4096, 3072);
  k_f2bs<<<1024, 256, 0, stream>>>(We, 2048, Web, 2048, 0);
  k_f2bs<<<512, 256, 0, stream>>>(Wd, 1024, Wdb, 1024, 0);
  k_f2bs<<<5000, 256, 0, stream>>>(Wfc1, 1024, Wfc1b, 1024, 0);
  k_f2bs<<<5000, 256, 0, stream>>>(Wfc, 1024, Wfcb, 1024, 0);
  k_att1_mfma<<<dim3(98, 4), 512, 0, stream>>>(encb, Web, be, att1);

  // ---- decode loop ----
  for (int t = 0; t < TDEC_; ++t) {
    k_embt<<<256, 256, 0, stream>>>(emb, caps_s, t, xc1);
    // LSTM1 gates: xc1[64x5120] @ Wcat1^T   (K=5120, KS=4 -> 1280)
    k_skinny<<<dim3(32, 4), 256, 0, stream>>>(xc1, 5120, Wc1, 5120, 4096, 1280, part);
    k_gates<<<256, 256, 0, stream>>>(part, bih1, bhh1, c1, xc1 + 4096, 5120, xc2 + 2048, 4096,
                                     declen, t);
    // att2 = h1 @ Wd^T  (K=1024, KS=2)
    k_skinny<<<dim3(8, 2), 256, 0, stream>>>(xc1 + 4096, 5120, Wdb, 1024, 1024, 512, att2p);
    k_e<<<3136, 256, 0, stream>>>(att1, att2p, bd, Wf, bf, alpha);
    k_softmax<<<64, 64, 0, stream>>>(alpha);
    k_awe<<<64, 256, 0, stream>>>(encb, alpha, xc2);
    // preds1 = h1 @ Wfc1^T  (K=1024, KS=2)
    k_skinny<<<dim3(79, 2), 256, 0, stream>>>(xc1 + 4096, 5120, Wfc1b, 1024, V_, 512, part);
    k_headfix<<<2500, 256, 0, stream>>>(part, bfc1, out_preds1 + (size_t)t * V_, declen, t);
    // LSTM2 gates: xc2[64x4096] @ Wcat2^T  (K=4096, KS=4 -> 1024)
    k_skinny<<<dim3(32, 4), 256, 0, stream>>>(xc2, 4096, Wc2, 4096, 4096, 1024, part);
    k_gates<<<256, 256, 0, stream>>>(part, bih2, bhh2, c2, xc2 + 3072, 4096, xc1, 5120,
                                     declen, t);
    // preds = h2 @ Wfc^T  (K=1024, KS=2)
    k_skinny<<<dim3(79, 2), 256, 0, stream>>>(xc2 + 3072, 4096, Wfcb, 1024, V_, 512, part);
    k_headfix<<<2500, 256, 0, stream>>>(part, bfc, out_preds + (size_t)t * V_, declen, t);
  }
}